// Round 16
// baseline (412.456 us; speedup 1.0000x reference)
//
#include <hip/hip_runtime.h>
#include <hip/hip_bf16.h>
#include <math.h>

#define NROW 8192
#define DD   128

// v16 = r15 (proven 87.5us) + defer-combine pipeline in the tile loop
#define V8BLK  256
#define V8NBLK 1024
#define NRANKV8 8128

// fallback geometry (round-2 proven)
#define NT   64
#define TS   128
#define NPAIR 2080
#define FBLOCK 512

#define LOG_2PI 1.8378770664093453f
#define L2E     1.4426950408889634f
#define FP_SCALE 1099511627776.0   // 2^40 (fallback only)

typedef __attribute__((ext_vector_type(8))) short bf16x8;
typedef __attribute__((ext_vector_type(4))) float f32x4;
typedef __attribute__((ext_vector_type(2))) float f32x2;

// ---- ws byte layout (r11/r15, proven) ----
#define SQX_B 0
#define SQY_B 32768
#define BSUM_B 65536
#define XB_B  65792
#define YB_B  (XB_B + NROW*DD*2)
#define TS_B  (YB_B + NROW*DD*2)                  // 4,260,096
#define COLV8_B  TS_B                             // 8128*192*4 = 6,242,304
#define ROWSV8_B (COLV8_B + NRANKV8*192*4)        // 2048*192*4 = 1,572,864
#define PS_B     (ROWSV8_B + 2048*192*4)          // 128*8*192*4 = 786,432
#define V8_NEED  (PS_B + 128*8*192*4)             // 12,861,696
#define ACC_B TS_B                                // fallback overlays

__device__ __forceinline__ unsigned short f2bf(float f) {
    unsigned int x = __float_as_uint(f);
    unsigned int r = (x + 0x7fffu + ((x >> 16) & 1u)) >> 16;  // RNE
    return (unsigned short)r;
}
__device__ __forceinline__ float fexp2(float x) { return __builtin_amdgcn_exp2f(x); }
__device__ __forceinline__ int rank_v8(int I, int J) {       // I<J on 128-grid
    return I * 127 - (I * (I - 1)) / 2 + (J - I - 1);
}

// ---------------- row squared norms (+ optional bf16 precopy) ----------------
template <bool PRE>
__global__ void sq_kernel(const float* __restrict__ X, const float* __restrict__ Y,
                          float* __restrict__ sqx, float* __restrict__ sqy,
                          unsigned short* __restrict__ XB, unsigned short* __restrict__ YB) {
    int tid  = threadIdx.x;
    int rowg = blockIdx.x * 8 + (tid >> 5);
    int lane = tid & 31;
    bool isX = rowg < NROW;
    const float* src = isX ? (X + (size_t)rowg * DD) : (Y + (size_t)(rowg - NROW) * DD);
    float4 v = reinterpret_cast<const float4*>(src)[lane];
    if (PRE) {
        unsigned int w0 = (unsigned int)f2bf(v.x) | ((unsigned int)f2bf(v.y) << 16);
        unsigned int w1 = (unsigned int)f2bf(v.z) | ((unsigned int)f2bf(v.w) << 16);
        unsigned short* dst = (isX ? XB + (size_t)rowg * DD
                                   : YB + (size_t)(rowg - NROW) * DD) + lane * 4;
        uint2 pk; pk.x = w0; pk.y = w1;
        *reinterpret_cast<uint2*>(dst) = pk;
    }
    float s = v.x * v.x + v.y * v.y + v.z * v.z + v.w * v.w;
#pragma unroll
    for (int m = 16; m; m >>= 1) s += __shfl_xor(s, m, 64);
    if (lane == 0) { if (isX) sqx[rowg] = s; else sqy[rowg - NROW] = s; }
}

// ================= PRIMARY: v8 + packed combine + defer-combine pipeline =================
template <bool SAME, bool DIAG>
__device__ __forceinline__ void combine_pk(const f32x4 (&ax)[4], const f32x4 (&ay)[4],
                                           const float* __restrict__ sqi0,
                                           const float* __restrict__ sqi1,
                                           float bxp, float byp,
                                           float cx2, float cy2, float m2cx, float m2cy,
                                           float rx, float ry,
                                           f32x2 (&prow)[4][2][3], f32x2 (&pcol)[3],
                                           int lane, int wq) {
    const int coll = wq * 16 + (lane & 15);
    const f32x2 bx2  = {bxp, bxp},  by2  = {byp, byp};
    const f32x2 cx22 = {cx2, cx2},  cy22 = {cy2, cy2};
    const f32x2 m2x2 = {m2cx, m2cx}, m2y2 = {m2cy, m2cy};
#pragma unroll
    for (int rf = 0; rf < 4; ++rf) {
        const int rb = rf * 16 + ((lane >> 4) << 2);
        const f32x2* six2 = reinterpret_cast<const f32x2*>(&sqi0[rb]);
        const f32x2* siy2 = reinterpret_cast<const f32x2*>(&sqi1[rb]);
#pragma unroll
        for (int h = 0; h < 2; ++h) {
            f32x2 axp = { ax[rf][2 * h], ax[rf][2 * h + 1] };
            f32x2 ayp = { ay[rf][2 * h], ay[rf][2 * h + 1] };
            f32x2 tx = __builtin_elementwise_fma(axp, m2x2,
                         __builtin_elementwise_fma(cx22, six2[h], bx2));
            f32x2 ty = __builtin_elementwise_fma(ayp, m2y2,
                         __builtin_elementwise_fma(cy22, siy2[h], by2));
            f32x2 ex, ey, ej;
            ex[0] = fexp2(tx[0]); ex[1] = fexp2(tx[1]);
            ey[0] = fexp2(ty[0]); ey[1] = fexp2(ty[1]);
            if (SAME) ej = ex * ey;
            else { ej[0] = fexp2(fmaf(tx[0], rx, ty[0] * ry));
                   ej[1] = fexp2(fmaf(tx[1], rx, ty[1] * ry)); }
            if (DIAG) {
                bool dg0 = (rb + 2 * h)     == coll;
                bool dg1 = (rb + 2 * h + 1) == coll;
                ex[0] = dg0 ? 1.f : ex[0];  ey[0] = dg0 ? 1.f : ey[0];  ej[0] = dg0 ? 1.f : ej[0];
                ex[1] = dg1 ? 1.f : ex[1];  ey[1] = dg1 ? 1.f : ey[1];  ej[1] = dg1 ? 1.f : ej[1];
            }
            prow[rf][h][0] += ex; prow[rf][h][1] += ey; prow[rf][h][2] += ej;
            pcol[0] += ex;        pcol[1] += ey;        pcol[2] += ej;
        }
    }
}

template <bool SAME>
__device__ __forceinline__ void pend_combine(const f32x4 (&ax)[4], const f32x4 (&ay)[4],
                                             const float* __restrict__ sqi0,
                                             const float* __restrict__ sqi1,
                                             float pbx, float pby,
                                             float cx2, float cy2, float m2cx, float m2cy,
                                             float rx, float ry, bool pdiag, int prk,
                                             f32x2 (&prow)[4][2][3],
                                             float* __restrict__ COL, int lane, int wq) {
    f32x2 pcol[3] = {{0.f,0.f},{0.f,0.f},{0.f,0.f}};
    if (pdiag) combine_pk<SAME, true >(ax, ay, sqi0, sqi1, pbx, pby, cx2, cy2, m2cx, m2cy, rx, ry, prow, pcol, lane, wq);
    else       combine_pk<SAME, false>(ax, ay, sqi0, sqi1, pbx, pby, cx2, cy2, m2cx, m2cy, rx, ry, prow, pcol, lane, wq);
    if (!pdiag) {
#pragma unroll
        for (int ch = 0; ch < 3; ++ch) {
            float v = pcol[ch][0] + pcol[ch][1];
            v += __shfl_xor(v, 16, 64);
            v += __shfl_xor(v, 32, 64);
            if (lane < 16)
                COL[((size_t)prk * 3 + ch) * 64 + wq * 16 + lane] = v;
        }
    }
}

__launch_bounds__(V8BLK, 1)
__global__ void kde_v8(const unsigned short* __restrict__ XB,
                       const unsigned short* __restrict__ YB,
                       const float* __restrict__ sjp, const float* __restrict__ sxp,
                       const float* __restrict__ syp,
                       const float* __restrict__ sqx, const float* __restrict__ sqy,
                       float* __restrict__ COL, float* __restrict__ ROWS) {
    __shared__ unsigned short A[2][64][DD];
    __shared__ float sqi[2][64];
    __shared__ float rowred[4][64][3];

    const int tid  = threadIdx.x;
    const int lane = tid & 63;
    const int wq   = tid >> 6;

    const int bid = blockIdx.x;
    const int cch = bid & 15;
    const int p   = bid >> 4;
    const int t0  = (129 * cch) >> 4;
    const int t1  = (129 * (cch + 1)) >> 4;

    const float sxv = *sxp, syv = *syp, sjv = *sjp;
    const float cx2 = -0.5f * L2E / (sxv * sxv);
    const float cy2 = -0.5f * L2E / (syv * syv);
    const float cj2 = -0.5f * L2E / (sjv * sjv);
    const bool  same = (cx2 == cy2) && (cy2 == cj2);
    const float m2cx = -2.f * cx2, m2cy = -2.f * cy2;
    const float rx = cj2 / cx2, ry = cj2 / cy2;

    f32x2 prow[4][2][3];
#pragma unroll
    for (int a = 0; a < 4; ++a)
#pragma unroll
        for (int h = 0; h < 2; ++h)
#pragma unroll
            for (int c = 0; c < 3; ++c) prow[a][h][c] = (f32x2){0.f, 0.f};

    f32x4 ax[4], ay[4];            // accumulator: consumed by pend combine, refilled by MFMA
    bool  pend = false, pdiag = false;
    int   prk = 0;
    float pbx = 0.f, pby = 0.f;

    int  curI = -1;
    bool wrote0 = false, wrote1 = false;

    for (int m = t0; m < t1; ++m) {
        int I, J;
        if (m < 128 - p) { I = p;       J = p + m; }
        else             { I = 127 - p; J = m - 1; }
        const bool diag = (I == J);
        const int j0 = J * 64;

        if (I != curI) {
            const bool hadPrev = (curI >= 0);
            const int prevWhich = (curI == p) ? 0 : 1;
            // finish pending tile against OLD band's sqi (before restage)
            if (pend) {
                if (same) pend_combine<true >(ax, ay, &sqi[0][0], &sqi[1][0], pbx, pby, cx2, cy2, m2cx, m2cy, rx, ry, pdiag, prk, prow, COL, lane, wq);
                else      pend_combine<false>(ax, ay, &sqi[0][0], &sqi[1][0], pbx, pby, cx2, cy2, m2cx, m2cy, rx, ry, pdiag, prk, prow, COL, lane, wq);
                pend = false;
            }
            __syncthreads();
            if (hadPrev) {
#pragma unroll
                for (int rf = 0; rf < 4; ++rf)
#pragma unroll
                    for (int h = 0; h < 2; ++h)
#pragma unroll
                        for (int c2 = 0; c2 < 2; ++c2)
#pragma unroll
                            for (int ch = 0; ch < 3; ++ch) {
                                float v = prow[rf][h][ch][c2];
                                v += __shfl_xor(v, 1, 64);
                                v += __shfl_xor(v, 2, 64);
                                v += __shfl_xor(v, 4, 64);
                                v += __shfl_xor(v, 8, 64);
                                if ((lane & 15) == 0)
                                    rowred[wq][rf * 16 + ((lane >> 4) << 2) + 2 * h + c2][ch] = v;
                                prow[rf][h][ch][c2] = 0.f;
                            }
            }
            {
                int mat   = wq >> 1;
                int rband = (wq & 1) * 32;
                const unsigned short* gb = (mat ? YB : XB) + (size_t)(I * 64) * DD;
#pragma unroll
                for (int i = 0; i < 8; ++i) {
                    int row = rband + i * 4 + (lane >> 4);
                    uint4 v = *reinterpret_cast<const uint4*>(gb + (size_t)row * DD + (lane & 15) * 8);
                    int sl = (lane & 15) ^ (row & 7);
                    *reinterpret_cast<uint4*>(&A[mat][row][sl * 8]) = v;
                }
            }
            if (tid < 128) sqi[tid >> 6][tid & 63] = ((tid < 64) ? sqx : sqy)[I * 64 + (tid & 63)];
            __syncthreads();
            if (hadPrev && tid < 192) {
                int ch = tid >> 6, row = tid & 63;
                size_t slot = ((size_t)(p * 16 + cch) * 2 + prevWhich);
                ROWS[(slot * 3 + ch) * 64 + row] = rowred[0][row][ch] + rowred[1][row][ch]
                                                 + rowred[2][row][ch] + rowred[3][row][ch];
            }
            if (hadPrev) { if (prevWhich == 0) wrote0 = true; else wrote1 = true; }
            curI = I;
        }

        // ---- issue B loads for THIS tile (fly during previous tile's combine) ----
        const int colg = j0 + wq * 16 + (lane & 15);
        bf16x8 bfx[4], bfy[4];
        {
            const unsigned short* px = XB + (size_t)colg * DD + ((lane >> 4) * 8);
            const unsigned short* py = YB + (size_t)colg * DD + ((lane >> 4) * 8);
#pragma unroll
            for (int kk = 0; kk < 4; ++kk) {
                bfx[kk] = *reinterpret_cast<const bf16x8*>(px + kk * 32);
                bfy[kk] = *reinterpret_cast<const bf16x8*>(py + kk * 32);
            }
        }
        const float nbx = cx2 * sqx[colg];
        const float nby = cy2 * sqy[colg];

        // ---- combine previous tile (B loads in flight) ----
        if (pend) {
            if (same) pend_combine<true >(ax, ay, &sqi[0][0], &sqi[1][0], pbx, pby, cx2, cy2, m2cx, m2cy, rx, ry, pdiag, prk, prow, COL, lane, wq);
            else      pend_combine<false>(ax, ay, &sqi[0][0], &sqi[1][0], pbx, pby, cx2, cy2, m2cx, m2cy, rx, ry, pdiag, prk, prow, COL, lane, wq);
        }

        // ---- MFMA this tile: A from LDS, B from regs ----
#pragma unroll
        for (int rf = 0; rf < 4; ++rf) {
            ax[rf] = (f32x4){0.f, 0.f, 0.f, 0.f};
            ay[rf] = (f32x4){0.f, 0.f, 0.f, 0.f};
        }
        __builtin_amdgcn_s_setprio(1);
#pragma unroll 2
        for (int kk = 0; kk < 4; ++kk) {
            bf16x8 afx[4], afy[4];
#pragma unroll
            for (int rf = 0; rf < 4; ++rf) {
                int r  = rf * 16 + (lane & 15);
                int sl = (kk * 4 + (lane >> 4)) ^ (r & 7);
                afx[rf] = *reinterpret_cast<const bf16x8*>(&A[0][r][sl * 8]);
                afy[rf] = *reinterpret_cast<const bf16x8*>(&A[1][r][sl * 8]);
            }
#pragma unroll
            for (int rf = 0; rf < 4; ++rf) {
                ax[rf] = __builtin_amdgcn_mfma_f32_16x16x32_bf16(afx[rf], bfx[kk], ax[rf], 0, 0, 0);
                ay[rf] = __builtin_amdgcn_mfma_f32_16x16x32_bf16(afy[rf], bfy[kk], ay[rf], 0, 0, 0);
            }
        }
        __builtin_amdgcn_s_setprio(0);

        pend = true; pdiag = diag; pbx = nbx; pby = nby;
        prk = diag ? 0 : rank_v8(I, J);
    }

    // ---- epilogue: combine last tile + final row flush ----
    if (pend) {
        if (same) pend_combine<true >(ax, ay, &sqi[0][0], &sqi[1][0], pbx, pby, cx2, cy2, m2cx, m2cy, rx, ry, pdiag, prk, prow, COL, lane, wq);
        else      pend_combine<false>(ax, ay, &sqi[0][0], &sqi[1][0], pbx, pby, cx2, cy2, m2cx, m2cy, rx, ry, pdiag, prk, prow, COL, lane, wq);
    }
    __syncthreads();
#pragma unroll
    for (int rf = 0; rf < 4; ++rf)
#pragma unroll
        for (int h = 0; h < 2; ++h)
#pragma unroll
            for (int c2 = 0; c2 < 2; ++c2)
#pragma unroll
                for (int ch = 0; ch < 3; ++ch) {
                    float v = prow[rf][h][ch][c2];
                    v += __shfl_xor(v, 1, 64);
                    v += __shfl_xor(v, 2, 64);
                    v += __shfl_xor(v, 4, 64);
                    v += __shfl_xor(v, 8, 64);
                    if ((lane & 15) == 0)
                        rowred[wq][rf * 16 + ((lane >> 4) << 2) + 2 * h + c2][ch] = v;
                }
    __syncthreads();
    {
        const int lastWhich = (curI == p) ? 0 : 1;
        if (tid < 192) {
            int ch = tid >> 6, row = tid & 63;
            size_t slot = ((size_t)(p * 16 + cch) * 2 + lastWhich);
            ROWS[(slot * 3 + ch) * 64 + row] = rowred[0][row][ch] + rowred[1][row][ch]
                                             + rowred[2][row][ch] + rowred[3][row][ch];
        }
        if (lastWhich == 0) wrote0 = true; else wrote1 = true;
    }
    if (!wrote0 && tid < 192) {
        int ch = tid >> 6, row = tid & 63;
        ROWS[(((size_t)(p * 16 + cch) * 2 + 0) * 3 + ch) * 64 + row] = 0.f;
    }
    if (!wrote1 && tid < 192) {
        int ch = tid >> 6, row = tid & 63;
        ROWS[(((size_t)(p * 16 + cch) * 2 + 1) * 3 + ch) * 64 + row] = 0.f;
    }
}

// ---- coalesced per-J column-sum partials ----
__global__ void colsum_v8(const float* __restrict__ COL, float* __restrict__ PS) {
    const int J = blockIdx.x;     // [0,128)
    const int s = blockIdx.y;     // [0,8)
    const int t = threadIdx.x;    // 192
    const int i0 = (J * s) >> 3;
    const int i1 = (J * (s + 1)) >> 3;
    float v = 0.f;
    for (int I = i0; I < i1; ++I)
        v += COL[(size_t)rank_v8(I, J) * 192 + t];
    PS[((size_t)J * 8 + s) * 192 + t] = v;
}

__global__ void lp_v8(const float* __restrict__ sjp, const float* __restrict__ sxp,
                      const float* __restrict__ syp,
                      const float* __restrict__ PS, const float* __restrict__ ROWS,
                      float* __restrict__ bsum) {
    int b = blockIdx.x;    // [0,64)
    int t = threadIdx.x;   // 128
    int r = b * 128 + t;
    int Ib = r >> 6;       // 64-row band [0,128)
    int c  = r & 63;
    float S0 = 0.f, S1 = 0.f, S2 = 0.f;
    {
        int p = (Ib < 64) ? Ib : 127 - Ib;
        int which = (Ib < 64) ? 0 : 1;
        for (int ch4 = 0; ch4 < 16; ++ch4) {
            size_t slot = ((size_t)(p * 16 + ch4) * 2 + which) * 3;
            S0 += ROWS[(slot + 0) * 64 + c];
            S1 += ROWS[(slot + 1) * 64 + c];
            S2 += ROWS[(slot + 2) * 64 + c];
        }
    }
    for (int s = 0; s < 8; ++s) {
        size_t base = ((size_t)Ib * 8 + s) * 192 + c;
        S0 += PS[base];
        S1 += PS[base + 64];
        S2 += PS[base + 128];
    }
    float sx = *sxp, sy = *syp, sj = *sjp;
    float logN = logf((float)NROW);
    float lpx = logf(S0) - (float)DD * logf(sx) - 0.5f * (float)DD * LOG_2PI - logN;
    float lpy = logf(S1) - (float)DD * logf(sy) - 0.5f * (float)DD * LOG_2PI - logN;
    float lpj = logf(S2) - 2.0f * (float)DD * logf(sj) - (float)DD * LOG_2PI - logN;
    float I_ = expf(lpj) * (lpj - lpx - lpy);
#pragma unroll
    for (int m = 1; m < 64; m <<= 1) I_ += __shfl_xor(I_, m, 64);
    __shared__ float w0s[2];
    if ((t & 63) == 0) w0s[t >> 6] = I_;
    __syncthreads();
    if (t == 0) bsum[b] = w0s[0] + w0s[1];
}

__global__ void final_reduce(const float* __restrict__ bsum, float* __restrict__ out) {
    int t = threadIdx.x;   // 64
    float v = bsum[t];
#pragma unroll
    for (int m = 1; m < 64; m <<= 1) v += __shfl_xor(v, m, 64);
    if (t == 0) out[0] = -v;
}

// ================= FALLBACK (round-2 proven; only if ws too small) =================
template <bool SAME>
__device__ __forceinline__ void fb_combine(const f32x4 (&ax)[4][2], const f32x4 (&ay)[4][2],
                                           const float (&sq)[4][TS],
                                           float (&rowred)[4][TS][3], float (&colred)[2][TS][3],
                                           int wr, int wc, int lane,
                                           float cx2, float cy2, float cj2) {
    float pcol[2][3] = {{0.f,0.f,0.f},{0.f,0.f,0.f}};
#pragma unroll
    for (int rf = 0; rf < 4; ++rf) {
        float prow[4][3] = {{0.f,0.f,0.f},{0.f,0.f,0.f},{0.f,0.f,0.f},{0.f,0.f,0.f}};
        float sxi[4], syi[4];
#pragma unroll
        for (int reg = 0; reg < 4; ++reg) {
            int row = wr*64 + rf*16 + ((lane>>4)<<2) + reg;
            sxi[reg] = sq[0][row]; syi[reg] = sq[1][row];
        }
#pragma unroll
        for (int cf = 0; cf < 2; ++cf) {
            int col = wc*32 + cf*16 + (lane & 15);
            float qx = sq[2][col], qy = sq[3][col];
#pragma unroll
            for (int reg = 0; reg < 4; ++reg) {
                float gx = ax[rf][cf][reg], gy = ay[rf][cf][reg];
                float d2x = fmaxf(fmaf(-2.f, gx, sxi[reg] + qx), 0.f);
                float d2y = fmaxf(fmaf(-2.f, gy, syi[reg] + qy), 0.f);
                float ex = fexp2(d2x * cx2);
                float ey = fexp2(d2y * cy2);
                float ej = SAME ? (ex * ey) : fexp2(fmaf(d2y, cj2, d2x * cj2));
                prow[reg][0] += ex; prow[reg][1] += ey; prow[reg][2] += ej;
                pcol[cf][0]  += ex; pcol[cf][1]  += ey; pcol[cf][2]  += ej;
            }
        }
#pragma unroll
        for (int reg = 0; reg < 4; ++reg)
#pragma unroll
            for (int ch = 0; ch < 3; ++ch) {
                float v = prow[reg][ch];
                v += __shfl_xor(v, 1, 64); v += __shfl_xor(v, 2, 64);
                v += __shfl_xor(v, 4, 64); v += __shfl_xor(v, 8, 64);
                if ((lane & 15) == 0)
                    rowred[wc][wr*64 + rf*16 + ((lane>>4)<<2) + reg][ch] = v;
            }
    }
#pragma unroll
    for (int cf = 0; cf < 2; ++cf)
#pragma unroll
        for (int ch = 0; ch < 3; ++ch) {
            float v = pcol[cf][ch];
            v += __shfl_xor(v, 16, 64); v += __shfl_xor(v, 32, 64);
            if (lane < 16) colred[wr][wc*32 + cf*16 + lane][ch] = v;
        }
}

__launch_bounds__(FBLOCK)
__global__ void kde_fb(const float* __restrict__ X, const float* __restrict__ Y,
                       const float* __restrict__ sjp, const float* __restrict__ sxp,
                       const float* __restrict__ syp,
                       unsigned long long* __restrict__ acc,
                       const float* __restrict__ sqx, const float* __restrict__ sqy) {
    __shared__ unsigned short T[4][TS][DD];
    __shared__ float sq[4][TS];
    __shared__ float rowred[4][TS][3];
    __shared__ float colred[2][TS][3];

    const int tid  = threadIdx.x;
    const int lane = tid & 63;
    const int wid  = tid >> 6;
    const int wr   = wid >> 2;
    const int wc   = wid & 3;

    int b = (blockIdx.x & 7) * (NPAIR / 8) + (blockIdx.x >> 3);
    int ti = 0, rem = b;
    while (rem >= NT - ti) { rem -= NT - ti; ++ti; }
    int tj = ti + rem;
    const int i0 = ti * TS, j0 = tj * TS;

    const float sxv = *sxp, syv = *syp, sjv = *sjp;
    const float cx2 = -0.5f * L2E / (sxv * sxv);
    const float cy2 = -0.5f * L2E / (syv * syv);
    const float cj2 = -0.5f * L2E / (sjv * sjv);
    const bool samesig = (cx2 == cy2) && (cy2 == cj2);

    for (int c = tid; c < 8192; c += FBLOCK) {
        int t = c >> 11, row = (c >> 4) & 127, col8 = c & 15;
        const float* base =
            (t == 0) ? X + (size_t)i0 * DD : (t == 1) ? Y + (size_t)i0 * DD :
            (t == 2) ? X + (size_t)j0 * DD : Y + (size_t)j0 * DD;
        const float4* s4 = reinterpret_cast<const float4*>(base + row * DD + col8 * 8);
        float4 a = s4[0], bb = s4[1];
        unsigned int w0 = (unsigned int)f2bf(a.x)  | ((unsigned int)f2bf(a.y)  << 16);
        unsigned int w1 = (unsigned int)f2bf(a.z)  | ((unsigned int)f2bf(a.w)  << 16);
        unsigned int w2 = (unsigned int)f2bf(bb.x) | ((unsigned int)f2bf(bb.y) << 16);
        unsigned int w3 = (unsigned int)f2bf(bb.z) | ((unsigned int)f2bf(bb.w) << 16);
        uint4 pk = make_uint4(w0, w1, w2, w3);
        int sl = (col8 ^ (row & 7)) << 3;
        *reinterpret_cast<uint4*>(&T[t][row][sl]) = pk;
    }
    {
        int t = tid >> 7, r = tid & 127;
        const float* s = (t == 0) ? sqx + i0 : (t == 1) ? sqy + i0
                       : (t == 2) ? sqx + j0 : sqy + j0;
        sq[t][r] = s[r];
    }
    __syncthreads();

    f32x4 ax[4][2], ay[4][2];
#pragma unroll
    for (int rf = 0; rf < 4; ++rf)
#pragma unroll
        for (int cf = 0; cf < 2; ++cf) {
            ax[rf][cf] = (f32x4){0.f,0.f,0.f,0.f};
            ay[rf][cf] = (f32x4){0.f,0.f,0.f,0.f};
        }
#pragma unroll
    for (int kk = 0; kk < 4; ++kk) {
        const int k0 = kk * 4 + (lane >> 4);
        bf16x8 afx[4], afy[4], bfx[2], bfy[2];
#pragma unroll
        for (int rf = 0; rf < 4; ++rf) {
            int r  = wr * 64 + rf * 16 + (lane & 15);
            int sl = (k0 ^ (r & 7)) << 3;
            afx[rf] = *reinterpret_cast<const bf16x8*>(&T[0][r][sl]);
            afy[rf] = *reinterpret_cast<const bf16x8*>(&T[1][r][sl]);
        }
#pragma unroll
        for (int cf = 0; cf < 2; ++cf) {
            int r  = wc * 32 + cf * 16 + (lane & 15);
            int sl = (k0 ^ (r & 7)) << 3;
            bfx[cf] = *reinterpret_cast<const bf16x8*>(&T[2][r][sl]);
            bfy[cf] = *reinterpret_cast<const bf16x8*>(&T[3][r][sl]);
        }
#pragma unroll
        for (int rf = 0; rf < 4; ++rf)
#pragma unroll
            for (int cf = 0; cf < 2; ++cf) {
                ax[rf][cf] = __builtin_amdgcn_mfma_f32_16x16x32_bf16(afx[rf], bfx[cf], ax[rf][cf], 0, 0, 0);
                ay[rf][cf] = __builtin_amdgcn_mfma_f32_16x16x32_bf16(afy[rf], bfy[cf], ay[rf][cf], 0, 0, 0);
            }
    }

    if (samesig) fb_combine<true >(ax, ay, sq, rowred, colred, wr, wc, lane, cx2, cy2, cj2);
    else         fb_combine<false>(ax, ay, sq, rowred, colred, wr, wc, lane, cx2, cy2, cj2);
    __syncthreads();

    if (tid < TS) {
        int r = tid;
#pragma unroll
        for (int ch = 0; ch < 3; ++ch) {
            float v = rowred[0][r][ch] + rowred[1][r][ch] + rowred[2][r][ch] + rowred[3][r][ch];
            atomicAdd(&acc[(size_t)(i0 + r) * 3 + ch],
                      (unsigned long long)(long long)((double)v * FP_SCALE));
        }
    } else if (tid < 2 * TS && ti != tj) {
        int r = tid - TS;
#pragma unroll
        for (int ch = 0; ch < 3; ++ch) {
            float v = colred[0][r][ch] + colred[1][r][ch];
            atomicAdd(&acc[(size_t)(j0 + r) * 3 + ch],
                      (unsigned long long)(long long)((double)v * FP_SCALE));
        }
    }
}

__global__ void lp_fb(const float* __restrict__ sjp, const float* __restrict__ sxp,
                      const float* __restrict__ syp,
                      const unsigned long long* __restrict__ acc,
                      float* __restrict__ bsum) {
    int b = blockIdx.x, t = threadIdx.x;
    size_t row = (size_t)b * 128 + t;
    const double INV = 1.0 / FP_SCALE;
    float S0 = (float)((double)acc[row * 3 + 0] * INV);
    float S1 = (float)((double)acc[row * 3 + 1] * INV);
    float S2 = (float)((double)acc[row * 3 + 2] * INV);
    float sx = *sxp, sy = *syp, sj = *sjp;
    float logN = logf((float)NROW);
    float lpx = logf(S0) - (float)DD * logf(sx) - 0.5f * (float)DD * LOG_2PI - logN;
    float lpy = logf(S1) - (float)DD * logf(sy) - 0.5f * (float)DD * LOG_2PI - logN;
    float lpj = logf(S2) - 2.0f * (float)DD * logf(sj) - (float)DD * LOG_2PI - logN;
    float I = expf(lpj) * (lpj - lpx - lpy);
#pragma unroll
    for (int m = 1; m < 64; m <<= 1) I += __shfl_xor(I, m, 64);
    __shared__ float w0[2];
    if ((t & 63) == 0) w0[t >> 6] = I;
    __syncthreads();
    if (t == 0) bsum[b] = w0[0] + w0[1];
}

extern "C" void kernel_launch(void* const* d_in, const int* in_sizes, int n_in,
                              void* d_out, int out_size, void* d_ws, size_t ws_size,
                              hipStream_t stream) {
    (void)in_sizes; (void)n_in; (void)out_size;
    const float* X  = (const float*)d_in[0];
    const float* Y  = (const float*)d_in[1];
    const float* sj = (const float*)d_in[2];
    const float* sx = (const float*)d_in[3];
    const float* sy = (const float*)d_in[4];
    float* out = (float*)d_out;
    char*  w   = (char*)d_ws;

    float* SQX  = (float*)(w + SQX_B);
    float* SQY  = (float*)(w + SQY_B);
    float* BSUM = (float*)(w + BSUM_B);
    unsigned short* XB = (unsigned short*)(w + XB_B);
    unsigned short* YB = (unsigned short*)(w + YB_B);

    if (ws_size >= (size_t)V8_NEED) {
        float* COLS = (float*)(w + COLV8_B);
        float* ROWS = (float*)(w + ROWSV8_B);
        float* PS   = (float*)(w + PS_B);
        sq_kernel<true ><<<dim3(2048), dim3(256), 0, stream>>>(X, Y, SQX, SQY, XB, YB);
        kde_v8<<<dim3(V8NBLK), dim3(V8BLK), 0, stream>>>(XB, YB, sj, sx, sy, SQX, SQY, COLS, ROWS);
        colsum_v8<<<dim3(128, 8), dim3(192), 0, stream>>>(COLS, PS);
        lp_v8<<<dim3(64), dim3(128), 0, stream>>>(sj, sx, sy, PS, ROWS, BSUM);
    } else {
        unsigned long long* ACC = (unsigned long long*)(w + ACC_B);
        hipMemsetAsync(w + ACC_B, 0, NROW * 3 * sizeof(unsigned long long), stream);
        sq_kernel<false><<<dim3(2048), dim3(256), 0, stream>>>(X, Y, SQX, SQY, XB, YB);
        kde_fb<<<dim3(NPAIR), dim3(FBLOCK), 0, stream>>>(X, Y, sj, sx, sy, ACC, SQX, SQY);
        lp_fb<<<dim3(64), dim3(128), 0, stream>>>(sj, sx, sy, ACC, BSUM);
    }
    final_reduce<<<dim3(1), dim3(64), 0, stream>>>(BSUM, out);
}

// Round 17
// 87.122 us; speedup vs baseline: 4.7342x; 4.7342x over previous
//
#include <hip/hip_runtime.h>
#include <hip/hip_bf16.h>
#include <math.h>

#define NROW 8192
#define DD   128

// r17 = exact revert to r15 (proven best: 87.5us total, kde 72.5us)
#define V8BLK  256
#define V8NBLK 1024
#define NRANKV8 8128

// fallback geometry (round-2 proven)
#define NT   64
#define TS   128
#define NPAIR 2080
#define FBLOCK 512

#define LOG_2PI 1.8378770664093453f
#define L2E     1.4426950408889634f
#define FP_SCALE 1099511627776.0   // 2^40 (fallback only)

typedef __attribute__((ext_vector_type(8))) short bf16x8;
typedef __attribute__((ext_vector_type(4))) float f32x4;
typedef __attribute__((ext_vector_type(2))) float f32x2;

// ---- ws byte layout (r11/r15, proven) ----
#define SQX_B 0
#define SQY_B 32768
#define BSUM_B 65536
#define XB_B  65792
#define YB_B  (XB_B + NROW*DD*2)
#define TS_B  (YB_B + NROW*DD*2)                  // 4,260,096
#define COLV8_B  TS_B                             // 8128*192*4 = 6,242,304
#define ROWSV8_B (COLV8_B + NRANKV8*192*4)        // 2048*192*4 = 1,572,864
#define PS_B     (ROWSV8_B + 2048*192*4)          // 128*8*192*4 = 786,432
#define V8_NEED  (PS_B + 128*8*192*4)             // 12,861,696
#define ACC_B TS_B                                // fallback overlays

__device__ __forceinline__ unsigned short f2bf(float f) {
    unsigned int x = __float_as_uint(f);
    unsigned int r = (x + 0x7fffu + ((x >> 16) & 1u)) >> 16;  // RNE
    return (unsigned short)r;
}
__device__ __forceinline__ float fexp2(float x) { return __builtin_amdgcn_exp2f(x); }
__device__ __forceinline__ int rank_v8(int I, int J) {       // I<J on 128-grid
    return I * 127 - (I * (I - 1)) / 2 + (J - I - 1);
}

// ---------------- row squared norms (+ optional bf16 precopy) ----------------
template <bool PRE>
__global__ void sq_kernel(const float* __restrict__ X, const float* __restrict__ Y,
                          float* __restrict__ sqx, float* __restrict__ sqy,
                          unsigned short* __restrict__ XB, unsigned short* __restrict__ YB) {
    int tid  = threadIdx.x;
    int rowg = blockIdx.x * 8 + (tid >> 5);
    int lane = tid & 31;
    bool isX = rowg < NROW;
    const float* src = isX ? (X + (size_t)rowg * DD) : (Y + (size_t)(rowg - NROW) * DD);
    float4 v = reinterpret_cast<const float4*>(src)[lane];
    if (PRE) {
        unsigned int w0 = (unsigned int)f2bf(v.x) | ((unsigned int)f2bf(v.y) << 16);
        unsigned int w1 = (unsigned int)f2bf(v.z) | ((unsigned int)f2bf(v.w) << 16);
        unsigned short* dst = (isX ? XB + (size_t)rowg * DD
                                   : YB + (size_t)(rowg - NROW) * DD) + lane * 4;
        uint2 pk; pk.x = w0; pk.y = w1;
        *reinterpret_cast<uint2*>(dst) = pk;
    }
    float s = v.x * v.x + v.y * v.y + v.z * v.z + v.w * v.w;
#pragma unroll
    for (int m = 16; m; m >>= 1) s += __shfl_xor(s, m, 64);
    if (lane == 0) { if (isX) sqx[rowg] = s; else sqy[rowg - NROW] = s; }
}

// ================= PRIMARY: r11's kde_v8 + packed-f32 combine + setprio =================
template <bool SAME, bool DIAG>
__device__ __forceinline__ void combine_pk(const f32x4 (&ax)[4], const f32x4 (&ay)[4],
                                           const float* __restrict__ sqi0,
                                           const float* __restrict__ sqi1,
                                           float bxp, float byp,
                                           float cx2, float cy2, float m2cx, float m2cy,
                                           float rx, float ry,
                                           f32x2 (&prow)[4][2][3], f32x2 (&pcol)[3],
                                           int lane, int wq) {
    const int coll = wq * 16 + (lane & 15);
    const f32x2 bx2  = {bxp, bxp},  by2  = {byp, byp};
    const f32x2 cx22 = {cx2, cx2},  cy22 = {cy2, cy2};
    const f32x2 m2x2 = {m2cx, m2cx}, m2y2 = {m2cy, m2cy};
#pragma unroll
    for (int rf = 0; rf < 4; ++rf) {
        const int rb = rf * 16 + ((lane >> 4) << 2);
        const f32x2* six2 = reinterpret_cast<const f32x2*>(&sqi0[rb]);
        const f32x2* siy2 = reinterpret_cast<const f32x2*>(&sqi1[rb]);
#pragma unroll
        for (int h = 0; h < 2; ++h) {
            f32x2 axp = { ax[rf][2 * h], ax[rf][2 * h + 1] };
            f32x2 ayp = { ay[rf][2 * h], ay[rf][2 * h + 1] };
            f32x2 tx = __builtin_elementwise_fma(axp, m2x2,
                         __builtin_elementwise_fma(cx22, six2[h], bx2));
            f32x2 ty = __builtin_elementwise_fma(ayp, m2y2,
                         __builtin_elementwise_fma(cy22, siy2[h], by2));
            f32x2 ex, ey, ej;
            ex[0] = fexp2(tx[0]); ex[1] = fexp2(tx[1]);
            ey[0] = fexp2(ty[0]); ey[1] = fexp2(ty[1]);
            if (SAME) ej = ex * ey;
            else { ej[0] = fexp2(fmaf(tx[0], rx, ty[0] * ry));
                   ej[1] = fexp2(fmaf(tx[1], rx, ty[1] * ry)); }
            if (DIAG) {
                bool dg0 = (rb + 2 * h)     == coll;
                bool dg1 = (rb + 2 * h + 1) == coll;
                ex[0] = dg0 ? 1.f : ex[0];  ey[0] = dg0 ? 1.f : ey[0];  ej[0] = dg0 ? 1.f : ej[0];
                ex[1] = dg1 ? 1.f : ex[1];  ey[1] = dg1 ? 1.f : ey[1];  ej[1] = dg1 ? 1.f : ej[1];
            }
            prow[rf][h][0] += ex; prow[rf][h][1] += ey; prow[rf][h][2] += ej;
            pcol[0] += ex;        pcol[1] += ey;        pcol[2] += ej;
        }
    }
}

__launch_bounds__(V8BLK, 1)
__global__ void kde_v8(const unsigned short* __restrict__ XB,
                       const unsigned short* __restrict__ YB,
                       const float* __restrict__ sjp, const float* __restrict__ sxp,
                       const float* __restrict__ syp,
                       const float* __restrict__ sqx, const float* __restrict__ sqy,
                       float* __restrict__ COL, float* __restrict__ ROWS) {
    __shared__ unsigned short A[2][64][DD];
    __shared__ float sqi[2][64];
    __shared__ float rowred[4][64][3];

    const int tid  = threadIdx.x;
    const int lane = tid & 63;
    const int wq   = tid >> 6;

    const int bid = blockIdx.x;
    const int cch = bid & 15;
    const int p   = bid >> 4;
    const int t0  = (129 * cch) >> 4;
    const int t1  = (129 * (cch + 1)) >> 4;

    const float sxv = *sxp, syv = *syp, sjv = *sjp;
    const float cx2 = -0.5f * L2E / (sxv * sxv);
    const float cy2 = -0.5f * L2E / (syv * syv);
    const float cj2 = -0.5f * L2E / (sjv * sjv);
    const bool  same = (cx2 == cy2) && (cy2 == cj2);
    const float m2cx = -2.f * cx2, m2cy = -2.f * cy2;
    const float rx = cj2 / cx2, ry = cj2 / cy2;

    f32x2 prow[4][2][3];
#pragma unroll
    for (int a = 0; a < 4; ++a)
#pragma unroll
        for (int h = 0; h < 2; ++h)
#pragma unroll
            for (int c = 0; c < 3; ++c) prow[a][h][c] = (f32x2){0.f, 0.f};

    int  curI = -1;
    bool wrote0 = false, wrote1 = false;

    for (int m = t0; m < t1; ++m) {
        int I, J;
        if (m < 128 - p) { I = p;       J = p + m; }
        else             { I = 127 - p; J = m - 1; }
        const bool diag = (I == J);
        const int j0 = J * 64;

        if (I != curI) {
            const bool hadPrev = (curI >= 0);
            const int prevWhich = (curI == p) ? 0 : 1;
            __syncthreads();
            if (hadPrev) {
#pragma unroll
                for (int rf = 0; rf < 4; ++rf)
#pragma unroll
                    for (int h = 0; h < 2; ++h)
#pragma unroll
                        for (int c2 = 0; c2 < 2; ++c2)
#pragma unroll
                            for (int ch = 0; ch < 3; ++ch) {
                                float v = prow[rf][h][ch][c2];
                                v += __shfl_xor(v, 1, 64);
                                v += __shfl_xor(v, 2, 64);
                                v += __shfl_xor(v, 4, 64);
                                v += __shfl_xor(v, 8, 64);
                                if ((lane & 15) == 0)
                                    rowred[wq][rf * 16 + ((lane >> 4) << 2) + 2 * h + c2][ch] = v;
                                prow[rf][h][ch][c2] = 0.f;
                            }
            }
            {
                int mat   = wq >> 1;
                int rband = (wq & 1) * 32;
                const unsigned short* gb = (mat ? YB : XB) + (size_t)(I * 64) * DD;
#pragma unroll
                for (int i = 0; i < 8; ++i) {
                    int row = rband + i * 4 + (lane >> 4);
                    uint4 v = *reinterpret_cast<const uint4*>(gb + (size_t)row * DD + (lane & 15) * 8);
                    int sl = (lane & 15) ^ (row & 7);
                    *reinterpret_cast<uint4*>(&A[mat][row][sl * 8]) = v;
                }
            }
            if (tid < 128) sqi[tid >> 6][tid & 63] = ((tid < 64) ? sqx : sqy)[I * 64 + (tid & 63)];
            __syncthreads();
            if (hadPrev && tid < 192) {
                int ch = tid >> 6, row = tid & 63;
                size_t slot = ((size_t)(p * 16 + cch) * 2 + prevWhich);
                ROWS[(slot * 3 + ch) * 64 + row] = rowred[0][row][ch] + rowred[1][row][ch]
                                                 + rowred[2][row][ch] + rowred[3][row][ch];
            }
            if (hadPrev) { if (prevWhich == 0) wrote0 = true; else wrote1 = true; }
            curI = I;
        }

        const int colg = j0 + wq * 16 + (lane & 15);
        const float bxp = cx2 * sqx[colg];
        const float byp = cy2 * sqy[colg];

        f32x4 ax[4], ay[4];
#pragma unroll
        for (int rf = 0; rf < 4; ++rf) {
            ax[rf] = (f32x4){0.f, 0.f, 0.f, 0.f};
            ay[rf] = (f32x4){0.f, 0.f, 0.f, 0.f};
        }
        __builtin_amdgcn_s_setprio(1);
#pragma unroll 2
        for (int kk = 0; kk < 4; ++kk) {
            bf16x8 bfx, bfy, afx[4], afy[4];
            {
                size_t off = (size_t)colg * DD + kk * 32 + (lane >> 4) * 8;
                bfx = *reinterpret_cast<const bf16x8*>(XB + off);
                bfy = *reinterpret_cast<const bf16x8*>(YB + off);
            }
#pragma unroll
            for (int rf = 0; rf < 4; ++rf) {
                int r  = rf * 16 + (lane & 15);
                int sl = (kk * 4 + (lane >> 4)) ^ (r & 7);
                afx[rf] = *reinterpret_cast<const bf16x8*>(&A[0][r][sl * 8]);
                afy[rf] = *reinterpret_cast<const bf16x8*>(&A[1][r][sl * 8]);
            }
#pragma unroll
            for (int rf = 0; rf < 4; ++rf) {
                ax[rf] = __builtin_amdgcn_mfma_f32_16x16x32_bf16(afx[rf], bfx, ax[rf], 0, 0, 0);
                ay[rf] = __builtin_amdgcn_mfma_f32_16x16x32_bf16(afy[rf], bfy, ay[rf], 0, 0, 0);
            }
        }
        __builtin_amdgcn_s_setprio(0);

        f32x2 pcol[3] = {{0.f,0.f},{0.f,0.f},{0.f,0.f}};
        if (same) { if (diag) combine_pk<true , true >(ax, ay, &sqi[0][0], &sqi[1][0], bxp, byp, cx2, cy2, m2cx, m2cy, rx, ry, prow, pcol, lane, wq);
                    else      combine_pk<true , false>(ax, ay, &sqi[0][0], &sqi[1][0], bxp, byp, cx2, cy2, m2cx, m2cy, rx, ry, prow, pcol, lane, wq); }
        else      { if (diag) combine_pk<false, true >(ax, ay, &sqi[0][0], &sqi[1][0], bxp, byp, cx2, cy2, m2cx, m2cy, rx, ry, prow, pcol, lane, wq);
                    else      combine_pk<false, false>(ax, ay, &sqi[0][0], &sqi[1][0], bxp, byp, cx2, cy2, m2cx, m2cy, rx, ry, prow, pcol, lane, wq); }

        if (!diag) {
            int rank = rank_v8(I, J);
#pragma unroll
            for (int ch = 0; ch < 3; ++ch) {
                float v = pcol[ch][0] + pcol[ch][1];
                v += __shfl_xor(v, 16, 64);
                v += __shfl_xor(v, 32, 64);
                if (lane < 16)
                    COL[((size_t)rank * 3 + ch) * 64 + wq * 16 + lane] = v;
            }
        }
    }

    __syncthreads();
#pragma unroll
    for (int rf = 0; rf < 4; ++rf)
#pragma unroll
        for (int h = 0; h < 2; ++h)
#pragma unroll
            for (int c2 = 0; c2 < 2; ++c2)
#pragma unroll
                for (int ch = 0; ch < 3; ++ch) {
                    float v = prow[rf][h][ch][c2];
                    v += __shfl_xor(v, 1, 64);
                    v += __shfl_xor(v, 2, 64);
                    v += __shfl_xor(v, 4, 64);
                    v += __shfl_xor(v, 8, 64);
                    if ((lane & 15) == 0)
                        rowred[wq][rf * 16 + ((lane >> 4) << 2) + 2 * h + c2][ch] = v;
                }
    __syncthreads();
    {
        const int lastWhich = (curI == p) ? 0 : 1;
        if (tid < 192) {
            int ch = tid >> 6, row = tid & 63;
            size_t slot = ((size_t)(p * 16 + cch) * 2 + lastWhich);
            ROWS[(slot * 3 + ch) * 64 + row] = rowred[0][row][ch] + rowred[1][row][ch]
                                             + rowred[2][row][ch] + rowred[3][row][ch];
        }
        if (lastWhich == 0) wrote0 = true; else wrote1 = true;
    }
    if (!wrote0 && tid < 192) {
        int ch = tid >> 6, row = tid & 63;
        ROWS[(((size_t)(p * 16 + cch) * 2 + 0) * 3 + ch) * 64 + row] = 0.f;
    }
    if (!wrote1 && tid < 192) {
        int ch = tid >> 6, row = tid & 63;
        ROWS[(((size_t)(p * 16 + cch) * 2 + 1) * 3 + ch) * 64 + row] = 0.f;
    }
}

// ---- coalesced per-J column-sum partials ----
__global__ void colsum_v8(const float* __restrict__ COL, float* __restrict__ PS) {
    const int J = blockIdx.x;     // [0,128)
    const int s = blockIdx.y;     // [0,8)
    const int t = threadIdx.x;    // 192
    const int i0 = (J * s) >> 3;
    const int i1 = (J * (s + 1)) >> 3;
    float v = 0.f;
    for (int I = i0; I < i1; ++I)
        v += COL[(size_t)rank_v8(I, J) * 192 + t];
    PS[((size_t)J * 8 + s) * 192 + t] = v;
}

__global__ void lp_v8(const float* __restrict__ sjp, const float* __restrict__ sxp,
                      const float* __restrict__ syp,
                      const float* __restrict__ PS, const float* __restrict__ ROWS,
                      float* __restrict__ bsum) {
    int b = blockIdx.x;    // [0,64)
    int t = threadIdx.x;   // 128
    int r = b * 128 + t;
    int Ib = r >> 6;       // 64-row band [0,128)
    int c  = r & 63;
    float S0 = 0.f, S1 = 0.f, S2 = 0.f;
    {
        int p = (Ib < 64) ? Ib : 127 - Ib;
        int which = (Ib < 64) ? 0 : 1;
        for (int ch4 = 0; ch4 < 16; ++ch4) {
            size_t slot = ((size_t)(p * 16 + ch4) * 2 + which) * 3;
            S0 += ROWS[(slot + 0) * 64 + c];
            S1 += ROWS[(slot + 1) * 64 + c];
            S2 += ROWS[(slot + 2) * 64 + c];
        }
    }
    for (int s = 0; s < 8; ++s) {
        size_t base = ((size_t)Ib * 8 + s) * 192 + c;
        S0 += PS[base];
        S1 += PS[base + 64];
        S2 += PS[base + 128];
    }
    float sx = *sxp, sy = *syp, sj = *sjp;
    float logN = logf((float)NROW);
    float lpx = logf(S0) - (float)DD * logf(sx) - 0.5f * (float)DD * LOG_2PI - logN;
    float lpy = logf(S1) - (float)DD * logf(sy) - 0.5f * (float)DD * LOG_2PI - logN;
    float lpj = logf(S2) - 2.0f * (float)DD * logf(sj) - (float)DD * LOG_2PI - logN;
    float I_ = expf(lpj) * (lpj - lpx - lpy);
#pragma unroll
    for (int m = 1; m < 64; m <<= 1) I_ += __shfl_xor(I_, m, 64);
    __shared__ float w0s[2];
    if ((t & 63) == 0) w0s[t >> 6] = I_;
    __syncthreads();
    if (t == 0) bsum[b] = w0s[0] + w0s[1];
}

__global__ void final_reduce(const float* __restrict__ bsum, float* __restrict__ out) {
    int t = threadIdx.x;   // 64
    float v = bsum[t];
#pragma unroll
    for (int m = 1; m < 64; m <<= 1) v += __shfl_xor(v, m, 64);
    if (t == 0) out[0] = -v;
}

// ================= FALLBACK (round-2 proven; only if ws too small) =================
template <bool SAME>
__device__ __forceinline__ void fb_combine(const f32x4 (&ax)[4][2], const f32x4 (&ay)[4][2],
                                           const float (&sq)[4][TS],
                                           float (&rowred)[4][TS][3], float (&colred)[2][TS][3],
                                           int wr, int wc, int lane,
                                           float cx2, float cy2, float cj2) {
    float pcol[2][3] = {{0.f,0.f,0.f},{0.f,0.f,0.f}};
#pragma unroll
    for (int rf = 0; rf < 4; ++rf) {
        float prow[4][3] = {{0.f,0.f,0.f},{0.f,0.f,0.f},{0.f,0.f,0.f},{0.f,0.f,0.f}};
        float sxi[4], syi[4];
#pragma unroll
        for (int reg = 0; reg < 4; ++reg) {
            int row = wr*64 + rf*16 + ((lane>>4)<<2) + reg;
            sxi[reg] = sq[0][row]; syi[reg] = sq[1][row];
        }
#pragma unroll
        for (int cf = 0; cf < 2; ++cf) {
            int col = wc*32 + cf*16 + (lane & 15);
            float qx = sq[2][col], qy = sq[3][col];
#pragma unroll
            for (int reg = 0; reg < 4; ++reg) {
                float gx = ax[rf][cf][reg], gy = ay[rf][cf][reg];
                float d2x = fmaxf(fmaf(-2.f, gx, sxi[reg] + qx), 0.f);
                float d2y = fmaxf(fmaf(-2.f, gy, syi[reg] + qy), 0.f);
                float ex = fexp2(d2x * cx2);
                float ey = fexp2(d2y * cy2);
                float ej = SAME ? (ex * ey) : fexp2(fmaf(d2y, cj2, d2x * cj2));
                prow[reg][0] += ex; prow[reg][1] += ey; prow[reg][2] += ej;
                pcol[cf][0]  += ex; pcol[cf][1]  += ey; pcol[cf][2]  += ej;
            }
        }
#pragma unroll
        for (int reg = 0; reg < 4; ++reg)
#pragma unroll
            for (int ch = 0; ch < 3; ++ch) {
                float v = prow[reg][ch];
                v += __shfl_xor(v, 1, 64); v += __shfl_xor(v, 2, 64);
                v += __shfl_xor(v, 4, 64); v += __shfl_xor(v, 8, 64);
                if ((lane & 15) == 0)
                    rowred[wc][wr*64 + rf*16 + ((lane>>4)<<2) + reg][ch] = v;
            }
    }
#pragma unroll
    for (int cf = 0; cf < 2; ++cf)
#pragma unroll
        for (int ch = 0; ch < 3; ++ch) {
            float v = pcol[cf][ch];
            v += __shfl_xor(v, 16, 64); v += __shfl_xor(v, 32, 64);
            if (lane < 16) colred[wr][wc*32 + cf*16 + lane][ch] = v;
        }
}

__launch_bounds__(FBLOCK)
__global__ void kde_fb(const float* __restrict__ X, const float* __restrict__ Y,
                       const float* __restrict__ sjp, const float* __restrict__ sxp,
                       const float* __restrict__ syp,
                       unsigned long long* __restrict__ acc,
                       const float* __restrict__ sqx, const float* __restrict__ sqy) {
    __shared__ unsigned short T[4][TS][DD];
    __shared__ float sq[4][TS];
    __shared__ float rowred[4][TS][3];
    __shared__ float colred[2][TS][3];

    const int tid  = threadIdx.x;
    const int lane = tid & 63;
    const int wid  = tid >> 6;
    const int wr   = wid >> 2;
    const int wc   = wid & 3;

    int b = (blockIdx.x & 7) * (NPAIR / 8) + (blockIdx.x >> 3);
    int ti = 0, rem = b;
    while (rem >= NT - ti) { rem -= NT - ti; ++ti; }
    int tj = ti + rem;
    const int i0 = ti * TS, j0 = tj * TS;

    const float sxv = *sxp, syv = *syp, sjv = *sjp;
    const float cx2 = -0.5f * L2E / (sxv * sxv);
    const float cy2 = -0.5f * L2E / (syv * syv);
    const float cj2 = -0.5f * L2E / (sjv * sjv);
    const bool samesig = (cx2 == cy2) && (cy2 == cj2);

    for (int c = tid; c < 8192; c += FBLOCK) {
        int t = c >> 11, row = (c >> 4) & 127, col8 = c & 15;
        const float* base =
            (t == 0) ? X + (size_t)i0 * DD : (t == 1) ? Y + (size_t)i0 * DD :
            (t == 2) ? X + (size_t)j0 * DD : Y + (size_t)j0 * DD;
        const float4* s4 = reinterpret_cast<const float4*>(base + row * DD + col8 * 8);
        float4 a = s4[0], bb = s4[1];
        unsigned int w0 = (unsigned int)f2bf(a.x)  | ((unsigned int)f2bf(a.y)  << 16);
        unsigned int w1 = (unsigned int)f2bf(a.z)  | ((unsigned int)f2bf(a.w)  << 16);
        unsigned int w2 = (unsigned int)f2bf(bb.x) | ((unsigned int)f2bf(bb.y) << 16);
        unsigned int w3 = (unsigned int)f2bf(bb.z) | ((unsigned int)f2bf(bb.w) << 16);
        uint4 pk = make_uint4(w0, w1, w2, w3);
        int sl = (col8 ^ (row & 7)) << 3;
        *reinterpret_cast<uint4*>(&T[t][row][sl]) = pk;
    }
    {
        int t = tid >> 7, r = tid & 127;
        const float* s = (t == 0) ? sqx + i0 : (t == 1) ? sqy + i0
                       : (t == 2) ? sqx + j0 : sqy + j0;
        sq[t][r] = s[r];
    }
    __syncthreads();

    f32x4 ax[4][2], ay[4][2];
#pragma unroll
    for (int rf = 0; rf < 4; ++rf)
#pragma unroll
        for (int cf = 0; cf < 2; ++cf) {
            ax[rf][cf] = (f32x4){0.f,0.f,0.f,0.f};
            ay[rf][cf] = (f32x4){0.f,0.f,0.f,0.f};
        }
#pragma unroll
    for (int kk = 0; kk < 4; ++kk) {
        const int k0 = kk * 4 + (lane >> 4);
        bf16x8 afx[4], afy[4], bfx[2], bfy[2];
#pragma unroll
        for (int rf = 0; rf < 4; ++rf) {
            int r  = wr * 64 + rf * 16 + (lane & 15);
            int sl = (k0 ^ (r & 7)) << 3;
            afx[rf] = *reinterpret_cast<const bf16x8*>(&T[0][r][sl]);
            afy[rf] = *reinterpret_cast<const bf16x8*>(&T[1][r][sl]);
        }
#pragma unroll
        for (int cf = 0; cf < 2; ++cf) {
            int r  = wc * 32 + cf * 16 + (lane & 15);
            int sl = (k0 ^ (r & 7)) << 3;
            bfx[cf] = *reinterpret_cast<const bf16x8*>(&T[2][r][sl]);
            bfy[cf] = *reinterpret_cast<const bf16x8*>(&T[3][r][sl]);
        }
#pragma unroll
        for (int rf = 0; rf < 4; ++rf)
#pragma unroll
            for (int cf = 0; cf < 2; ++cf) {
                ax[rf][cf] = __builtin_amdgcn_mfma_f32_16x16x32_bf16(afx[rf], bfx[cf], ax[rf][cf], 0, 0, 0);
                ay[rf][cf] = __builtin_amdgcn_mfma_f32_16x16x32_bf16(afy[rf], bfy[cf], ay[rf][cf], 0, 0, 0);
            }
    }

    if (samesig) fb_combine<true >(ax, ay, sq, rowred, colred, wr, wc, lane, cx2, cy2, cj2);
    else         fb_combine<false>(ax, ay, sq, rowred, colred, wr, wc, lane, cx2, cy2, cj2);
    __syncthreads();

    if (tid < TS) {
        int r = tid;
#pragma unroll
        for (int ch = 0; ch < 3; ++ch) {
            float v = rowred[0][r][ch] + rowred[1][r][ch] + rowred[2][r][ch] + rowred[3][r][ch];
            atomicAdd(&acc[(size_t)(i0 + r) * 3 + ch],
                      (unsigned long long)(long long)((double)v * FP_SCALE));
        }
    } else if (tid < 2 * TS && ti != tj) {
        int r = tid - TS;
#pragma unroll
        for (int ch = 0; ch < 3; ++ch) {
            float v = colred[0][r][ch] + colred[1][r][ch];
            atomicAdd(&acc[(size_t)(j0 + r) * 3 + ch],
                      (unsigned long long)(long long)((double)v * FP_SCALE));
        }
    }
}

__global__ void lp_fb(const float* __restrict__ sjp, const float* __restrict__ sxp,
                      const float* __restrict__ syp,
                      const unsigned long long* __restrict__ acc,
                      float* __restrict__ bsum) {
    int b = blockIdx.x, t = threadIdx.x;
    size_t row = (size_t)b * 128 + t;
    const double INV = 1.0 / FP_SCALE;
    float S0 = (float)((double)acc[row * 3 + 0] * INV);
    float S1 = (float)((double)acc[row * 3 + 1] * INV);
    float S2 = (float)((double)acc[row * 3 + 2] * INV);
    float sx = *sxp, sy = *syp, sj = *sjp;
    float logN = logf((float)NROW);
    float lpx = logf(S0) - (float)DD * logf(sx) - 0.5f * (float)DD * LOG_2PI - logN;
    float lpy = logf(S1) - (float)DD * logf(sy) - 0.5f * (float)DD * LOG_2PI - logN;
    float lpj = logf(S2) - 2.0f * (float)DD * logf(sj) - (float)DD * LOG_2PI - logN;
    float I = expf(lpj) * (lpj - lpx - lpy);
#pragma unroll
    for (int m = 1; m < 64; m <<= 1) I += __shfl_xor(I, m, 64);
    __shared__ float w0[2];
    if ((t & 63) == 0) w0[t >> 6] = I;
    __syncthreads();
    if (t == 0) bsum[b] = w0[0] + w0[1];
}

extern "C" void kernel_launch(void* const* d_in, const int* in_sizes, int n_in,
                              void* d_out, int out_size, void* d_ws, size_t ws_size,
                              hipStream_t stream) {
    (void)in_sizes; (void)n_in; (void)out_size;
    const float* X  = (const float*)d_in[0];
    const float* Y  = (const float*)d_in[1];
    const float* sj = (const float*)d_in[2];
    const float* sx = (const float*)d_in[3];
    const float* sy = (const float*)d_in[4];
    float* out = (float*)d_out;
    char*  w   = (char*)d_ws;

    float* SQX  = (float*)(w + SQX_B);
    float* SQY  = (float*)(w + SQY_B);
    float* BSUM = (float*)(w + BSUM_B);
    unsigned short* XB = (unsigned short*)(w + XB_B);
    unsigned short* YB = (unsigned short*)(w + YB_B);

    if (ws_size >= (size_t)V8_NEED) {
        float* COLS = (float*)(w + COLV8_B);
        float* ROWS = (float*)(w + ROWSV8_B);
        float* PS   = (float*)(w + PS_B);
        sq_kernel<true ><<<dim3(2048), dim3(256), 0, stream>>>(X, Y, SQX, SQY, XB, YB);
        kde_v8<<<dim3(V8NBLK), dim3(V8BLK), 0, stream>>>(XB, YB, sj, sx, sy, SQX, SQY, COLS, ROWS);
        colsum_v8<<<dim3(128, 8), dim3(192), 0, stream>>>(COLS, PS);
        lp_v8<<<dim3(64), dim3(128), 0, stream>>>(sj, sx, sy, PS, ROWS, BSUM);
    } else {
        unsigned long long* ACC = (unsigned long long*)(w + ACC_B);
        hipMemsetAsync(w + ACC_B, 0, NROW * 3 * sizeof(unsigned long long), stream);
        sq_kernel<false><<<dim3(2048), dim3(256), 0, stream>>>(X, Y, SQX, SQY, XB, YB);
        kde_fb<<<dim3(NPAIR), dim3(FBLOCK), 0, stream>>>(X, Y, sj, sx, sy, ACC, SQX, SQY);
        lp_fb<<<dim3(64), dim3(128), 0, stream>>>(sj, sx, sy, ACC, BSUM);
    }
    final_reduce<<<dim3(1), dim3(64), 0, stream>>>(BSUM, out);
}